// Round 6
// baseline (493.542 us; speedup 1.0000x reference)
//
#include <hip/hip_runtime.h>

// ConvLSTM2D x2 encoder — bf16 MFMA implicit-GEMM, round 6.
// Round-5 diagnosis: latency-bound on B(weight) L2 loads (all pipes <25%,
// dispatch pinned at 50us across 3 structures). Changes:
//  - M=128 per wave (16x8 block tile, acc[8][4]): 32 MFMA per 4-load B group
//    (was 16), so 2 waves/SIMD fully cover ~300cyc L2 latency.
//  - Explicit 1-ahead B prefetch (B[dy+1] loads issued before dy's MFMAs).
//  - Grid 512 blocks = 2 blocks/CU exact; one L0 + one L1 block per CU.

typedef __bf16 bf16x8 __attribute__((ext_vector_type(8)));
typedef float f32x4 __attribute__((ext_vector_type(4)));

#define BHWF (8 * 64 * 64 * 64)
#define TSTRIDE 72                // LDS cell stride (bf16 units), cell = 128B data + 16B pad
#define NCELL 180                 // 10 rows x 18 cols halo tile

__device__ __forceinline__ float hsig(float x) {
    return fminf(fmaxf(fmaf(0.2f, x, 0.5f), 0.0f), 1.0f);
}

__device__ __forceinline__ ushort f2bf(float f) {
    unsigned u = __float_as_uint(f);
    return (ushort)((u + 0x7FFFu + ((u >> 16) & 1u)) >> 16);
}

// Swizzle fp32 W[k=576][n=256] -> bf16 fragment-linear (same as round 4/5).
__global__ void prep_w(const float* __restrict__ s0, const float* __restrict__ s1,
                       const float* __restrict__ s2,
                       ushort* __restrict__ d0, ushort* __restrict__ d1,
                       ushort* __restrict__ d2) {
    const float* s[3] = { s0, s1, s2 };
    ushort* d[3] = { d0, d1, d2 };
    int o = blockIdx.x * 256 + threadIdx.x;
    int e    = o & 7;
    int lane = (o >> 3) & 63;
    int g    = (o >> 9) & 3;
    int fq   = (o >> 11) & 3;
    int kc   = (o >> 13) & 1;
    int tap  = o >> 14;
    int n = g * 64 + fq * 16 + (lane & 15);
    int k = tap * 64 + kc * 32 + (lane >> 4) * 8 + e;
    d[blockIdx.y][o] = f2bf(s[blockIdx.y][k * 256 + n]);
}

// Stage 10x18 halo tile of bf16 [4096][64] image into LDS [cell][TSTRIDE].
__device__ __forceinline__ void stage(const ushort* __restrict__ src,
                                      ushort* __restrict__ tile,
                                      int y0, int x0, int tid) {
    for (int v = tid; v < NCELL * 8; v += 256) {
        int cell = v >> 3, j = v & 7;
        int r = cell / 18, cc = cell - r * 18;
        int y = y0 - 1 + r, xx = x0 - 1 + cc;
        uint4 dv = make_uint4(0u, 0u, 0u, 0u);
        if ((unsigned)y < 64u && (unsigned)xx < 64u)
            dv = ((const uint4*)src)[(size_t)((y << 6) + xx) * 8 + j];
        *(uint4*)&tile[cell * TSTRIDE + j * 8] = dv;
    }
}

// 3x3x64 conv, M=128 (8 m-tiles), explicit 1-ahead B prefetch.
__device__ __forceinline__ void conv8(const ushort* __restrict__ tile,
                                      const ushort* __restrict__ WS,
                                      f32x4 (&acc)[8][4],
                                      int fq, int lane) {
    const int colA = lane & 15;
    const int quad = (lane >> 4) & 3;
    const ushort* wbase = WS + fq * 2048 + lane * 8;
    #pragma unroll
    for (int kc = 0; kc < 2; ++kc) {
        #pragma unroll
        for (int dx = 0; dx < 3; ++dx) {
            // A column for this dx: rows 0..9, reused across all 3 dy
            bf16x8 A[10];
            #pragma unroll
            for (int r = 0; r < 10; ++r)
                A[r] = *(const bf16x8*)&tile[(r * 18 + colA + dx) * TSTRIDE + kc * 32 + quad * 8];
            bf16x8 B[3][4];
            {
                const ushort* wp = wbase + (size_t)((dx) * 2 + kc) * 8192;  // tap (0,dx)
                #pragma unroll
                for (int g = 0; g < 4; ++g) B[0][g] = *(const bf16x8*)&wp[g * 512];
            }
            #pragma unroll
            for (int dy = 0; dy < 3; ++dy) {
                if (dy < 2) {   // prefetch next dy's B before consuming current
                    const ushort* wp = wbase + (size_t)(((dy + 1) * 3 + dx) * 2 + kc) * 8192;
                    #pragma unroll
                    for (int g = 0; g < 4; ++g) B[dy + 1][g] = *(const bf16x8*)&wp[g * 512];
                }
                #pragma unroll
                for (int mt = 0; mt < 8; ++mt)
                    #pragma unroll
                    for (int g = 0; g < 4; ++g)
                        acc[mt][g] = __builtin_amdgcn_mfma_f32_16x16x32_bf16(
                            A[mt + dy], B[dy][g], acc[mt][g], 0, 0, 0);
            }
        }
    }
}

// Merged step: z<8 -> L0 at time t, z>=8 -> L1 at time t-1 (independent work).
__global__ __launch_bounds__(256, 2) void step_merged(
    int l0_active, int l1_active, int last0, int last1,
    const float* __restrict__ x, const float* __restrict__ Wx0,
    const ushort* __restrict__ Wh0S, const float* __restrict__ b0,
    const ushort* __restrict__ h0_prev, float* __restrict__ c0,
    ushort* __restrict__ h0_out, float* __restrict__ oh0, float* __restrict__ oc0,
    const ushort* __restrict__ xin, const ushort* __restrict__ Wx1S,
    const ushort* __restrict__ Wh1S, const float* __restrict__ b1,
    const ushort* __restrict__ h1_prev, float* __restrict__ c1,
    ushort* __restrict__ h1_out, float* __restrict__ oh1, float* __restrict__ oc1)
{
    __shared__ __align__(16) ushort tile1[NCELL * TSTRIDE];
    __shared__ __align__(16) ushort tile2[NCELL * TSTRIDE];
    __shared__ float xtile[NCELL];

    const int z = blockIdx.z;
    bool isL1; int b;
    if (l0_active && l1_active) { isL1 = (z >= 8); b = z & 7; }
    else                        { isL1 = (l1_active != 0); b = z; }

    const int tid = threadIdx.x;
    const int lane = tid & 63;
    const int fq = tid >> 6;            // wave id = f quad
    const int colA = lane & 15;
    const int quad = (lane >> 4) & 3;
    const int x0 = blockIdx.x * 16, y0 = blockIdx.y * 8;
    const int f = fq * 16 + colA;

    const ushort* h_prev = isL1 ? h1_prev : h0_prev;
    const float*  bias   = isL1 ? b1 : b0;
    float*        cbuf   = isL1 ? c1 : c0;
    ushort*       hout   = isL1 ? h1_out : h0_out;
    float* hf = isL1 ? (last1 ? oh1 : nullptr) : (last0 ? oh0 : nullptr);
    float* cf = isL1 ? (last1 ? oc1 : nullptr) : (last0 ? oc0 : nullptr);

    // ---- stage ----
    if (!isL1) {
        const float* xs = x + (size_t)b * 40960;
        for (int v = tid; v < NCELL; v += 256) {
            int r = v / 18, cc = v - r * 18;
            int y = y0 - 1 + r, xx = x0 - 1 + cc;
            xtile[v] = ((unsigned)y < 64u && (unsigned)xx < 64u) ? xs[(y << 6) + xx] : 0.f;
        }
        if (h_prev) stage(h_prev + (size_t)b * 4096 * 64, tile1, y0, x0, tid);
    } else {
        stage(xin + (size_t)b * 4096 * 64, tile1, y0, x0, tid);
        if (h_prev) stage(h_prev + (size_t)b * 4096 * 64, tile2, y0, x0, tid);
    }
    __syncthreads();

    // ---- init accumulators with bias ----
    f32x4 acc[8][4];
    #pragma unroll
    for (int g = 0; g < 4; ++g) {
        float bv = bias[g * 64 + f];
        #pragma unroll
        for (int mt = 0; mt < 8; ++mt) {
            acc[mt][g][0] = bv; acc[mt][g][1] = bv;
            acc[mt][g][2] = bv; acc[mt][g][3] = bv;
        }
    }

    if (!isL1) {
        // scalar x-conv (Cin=1)
        float wx[9][4];
        #pragma unroll
        for (int tap = 0; tap < 9; ++tap)
            #pragma unroll
            for (int g = 0; g < 4; ++g)
                wx[tap][g] = Wx0[tap * 256 + g * 64 + f];
        #pragma unroll
        for (int mt = 0; mt < 8; ++mt) {
            #pragma unroll
            for (int reg = 0; reg < 4; ++reg) {
                const int cc = quad * 4 + reg;
                float s0 = 0.f, s1 = 0.f, s2 = 0.f, s3 = 0.f;
                #pragma unroll
                for (int tap = 0; tap < 9; ++tap) {
                    int dy = tap / 3, dx = tap - dy * 3;
                    float xv = xtile[(mt + dy) * 18 + cc + dx];
                    s0 = fmaf(xv, wx[tap][0], s0);
                    s1 = fmaf(xv, wx[tap][1], s1);
                    s2 = fmaf(xv, wx[tap][2], s2);
                    s3 = fmaf(xv, wx[tap][3], s3);
                }
                acc[mt][0][reg] += s0; acc[mt][1][reg] += s1;
                acc[mt][2][reg] += s2; acc[mt][3][reg] += s3;
            }
        }
        if (h_prev) conv8(tile1, Wh0S, acc, fq, lane);
    } else {
        conv8(tile1, Wx1S, acc, fq, lane);
        if (h_prev) conv8(tile2, Wh1S, acc, fq, lane);
    }

    // ---- LSTM pointwise epilogue ----
    #pragma unroll
    for (int mt = 0; mt < 8; ++mt) {
        const int y = y0 + mt;
        #pragma unroll
        for (int reg = 0; reg < 4; ++reg) {
            const int xx = x0 + quad * 4 + reg;
            const size_t pidx = ((size_t)b * 4096 + (y << 6) + xx) * 64 + f;
            float cp = h_prev ? cbuf[pidx] : 0.f;
            float iv = hsig(acc[mt][0][reg]);
            float fv = hsig(acc[mt][1][reg]);
            float gv = tanhf(acc[mt][2][reg]);
            float ov = hsig(acc[mt][3][reg]);
            float cn = fmaf(fv, cp, iv * gv);
            float hn = ov * tanhf(cn);
            cbuf[pidx] = cn;
            hout[pidx] = f2bf(hn);
            if (hf) { hf[pidx] = hn; cf[pidx] = cn; }
        }
    }
}

extern "C" void kernel_launch(void* const* d_in, const int* in_sizes, int n_in,
                              void* d_out, int out_size, void* d_ws, size_t ws_size,
                              hipStream_t stream) {
    const float* x   = (const float*)d_in[0];
    const float* Wx0 = (const float*)d_in[1];
    const float* Wh0 = (const float*)d_in[2];
    const float* b0  = (const float*)d_in[3];
    const float* Wx1 = (const float*)d_in[4];
    const float* Wh1 = (const float*)d_in[5];
    const float* b1  = (const float*)d_in[6];
    float* out = (float*)d_out;
    char* ws = (char*)d_ws;

    ushort* h0buf[2] = { (ushort*)ws, (ushort*)(ws + 4u * 1024 * 1024) };
    ushort* h1buf[2] = { (ushort*)(ws + 8u * 1024 * 1024), (ushort*)(ws + 12u * 1024 * 1024) };
    float* c0 = (float*)(ws + 16u * 1024 * 1024);
    float* c1 = (float*)(ws + 24u * 1024 * 1024);
    ushort* Wh0S = (ushort*)(ws + 32u * 1024 * 1024);
    ushort* Wx1S = Wh0S + 147456;
    ushort* Wh1S = Wx1S + 147456;

    prep_w<<<dim3(576, 3), 256, 0, stream>>>(Wh0, Wx1, Wh1, Wh0S, Wx1S, Wh1S);

    for (int t = 0; t <= 10; ++t) {
        const int has0 = (t < 10), has1 = (t >= 1);
        const int s = t - 1;
        const int tx = has0 ? t : 9;
        dim3 grid(4, 8, (has0 && has1) ? 16 : 8);
        step_merged<<<grid, 256, 0, stream>>>(
            has0, has1, (t == 9), (s == 9),
            x + (size_t)tx * 4096, Wx0,
            (t >= 1) ? Wh0S : nullptr, b0,
            (t >= 1 && has0) ? h0buf[(t - 1) & 1] : nullptr, c0,
            h0buf[t & 1], out, out + BHWF,
            has1 ? h0buf[s & 1] : nullptr, Wx1S,
            Wh1S, b1,
            (s >= 1) ? h1buf[(s - 1) & 1] : nullptr, c1,
            h1buf[s & 1], out + 2 * (size_t)BHWF, out + 3 * (size_t)BHWF);
    }
}

// Round 7
// 465.782 us; speedup vs baseline: 1.0596x; 1.0596x over previous
//
#include <hip/hip_runtime.h>

// ConvLSTM2D x2 encoder — bf16 MFMA implicit-GEMM, round 7.
// Round-6 finding: 256 regs/wave exactly full (128 VGPR + 128 AGPR) — no
// pipelining headroom; VALU fat dominates the non-MFMA time. Changes:
//  - fast tanh (exp2+rcp, ~5 instr) in epilogue (was tanhf ~20+).
//  - Cin=1 x-conv via MFMA: Wx0 prepped K=32-padded fragment-linear; x-patch
//    A-fragments built into LDS im2col (xa, 8KB) during staging.
// Conv loop / tiling / occupancy untouched.

typedef __bf16 bf16x8 __attribute__((ext_vector_type(8)));
typedef float f32x4 __attribute__((ext_vector_type(4)));

#define BHWF (8 * 64 * 64 * 64)
#define TSTRIDE 72                // LDS cell stride (bf16 units)
#define NCELL 180                 // 10 rows x 18 cols halo tile

__device__ __forceinline__ float hsig(float x) {
    return fminf(fmaxf(fmaf(0.2f, x, 0.5f), 0.0f), 1.0f);
}

__device__ __forceinline__ float ftanh(float x) {
    // tanh(x) = 1 - 2/(e^{2x}+1); v_exp_f32 + v_rcp_f32, large-|x| safe.
    float e = __expf(2.0f * x);
    return fmaf(-2.0f, __builtin_amdgcn_rcpf(e + 1.0f), 1.0f);
}

__device__ __forceinline__ ushort f2bf(float f) {
    unsigned u = __float_as_uint(f);
    return (ushort)((u + 0x7FFFu + ((u >> 16) & 1u)) >> 16);
}

// y=0..2: swizzle fp32 W[k=576][n=256] -> bf16 fragment-linear (as round 4-6).
// y=3: Wx0 [9][256] -> K=32-padded fragment frames [fq][g][lane][e] (zeros k>=9).
__global__ void prep_w(const float* __restrict__ s0, const float* __restrict__ s1,
                       const float* __restrict__ s2, const float* __restrict__ wx0,
                       ushort* __restrict__ d0, ushort* __restrict__ d1,
                       ushort* __restrict__ d2, ushort* __restrict__ dx0) {
    int o = blockIdx.x * 256 + threadIdx.x;
    if (blockIdx.y == 3) {
        if (o < 8192) {
            int e    = o & 7;
            int lane = (o >> 3) & 63;
            int g    = (o >> 9) & 3;
            int fq   = (o >> 11) & 3;
            int k = (lane >> 4) * 8 + e;
            int n = g * 64 + fq * 16 + (lane & 15);
            dx0[o] = (k < 9) ? f2bf(wx0[k * 256 + n]) : (ushort)0;
        }
        return;
    }
    const float* s[3] = { s0, s1, s2 };
    ushort* d[3] = { d0, d1, d2 };
    int e    = o & 7;
    int lane = (o >> 3) & 63;
    int g    = (o >> 9) & 3;
    int fq   = (o >> 11) & 3;
    int kc   = (o >> 13) & 1;
    int tap  = o >> 14;
    int n = g * 64 + fq * 16 + (lane & 15);
    int k = tap * 64 + kc * 32 + (lane >> 4) * 8 + e;
    d[blockIdx.y][o] = f2bf(s[blockIdx.y][k * 256 + n]);
}

// Stage 10x18 halo tile of bf16 [4096][64] image into LDS [cell][TSTRIDE].
__device__ __forceinline__ void stage(const ushort* __restrict__ src,
                                      ushort* __restrict__ tile,
                                      int y0, int x0, int tid) {
    for (int v = tid; v < NCELL * 8; v += 256) {
        int cell = v >> 3, j = v & 7;
        int r = cell / 18, cc = cell - r * 18;
        int y = y0 - 1 + r, xx = x0 - 1 + cc;
        uint4 dv = make_uint4(0u, 0u, 0u, 0u);
        if ((unsigned)y < 64u && (unsigned)xx < 64u)
            dv = ((const uint4*)src)[(size_t)((y << 6) + xx) * 8 + j];
        *(uint4*)&tile[cell * TSTRIDE + j * 8] = dv;
    }
}

// 3x3x64 conv, M=128 (8 m-tiles), 1-ahead B prefetch (round-6 structure).
__device__ __forceinline__ void conv8(const ushort* __restrict__ tile,
                                      const ushort* __restrict__ WS,
                                      f32x4 (&acc)[8][4],
                                      int fq, int lane) {
    const int colA = lane & 15;
    const int quad = (lane >> 4) & 3;
    const ushort* wbase = WS + fq * 2048 + lane * 8;
    #pragma unroll
    for (int kc = 0; kc < 2; ++kc) {
        #pragma unroll
        for (int dx = 0; dx < 3; ++dx) {
            bf16x8 A[10];
            #pragma unroll
            for (int r = 0; r < 10; ++r)
                A[r] = *(const bf16x8*)&tile[(r * 18 + colA + dx) * TSTRIDE + kc * 32 + quad * 8];
            bf16x8 B[3][4];
            {
                const ushort* wp = wbase + (size_t)(dx * 2 + kc) * 8192;
                #pragma unroll
                for (int g = 0; g < 4; ++g) B[0][g] = *(const bf16x8*)&wp[g * 512];
            }
            #pragma unroll
            for (int dy = 0; dy < 3; ++dy) {
                if (dy < 2) {
                    const ushort* wp = wbase + (size_t)(((dy + 1) * 3 + dx) * 2 + kc) * 8192;
                    #pragma unroll
                    for (int g = 0; g < 4; ++g) B[dy + 1][g] = *(const bf16x8*)&wp[g * 512];
                }
                #pragma unroll
                for (int mt = 0; mt < 8; ++mt)
                    #pragma unroll
                    for (int g = 0; g < 4; ++g)
                        acc[mt][g] = __builtin_amdgcn_mfma_f32_16x16x32_bf16(
                            A[mt + dy], B[dy][g], acc[mt][g], 0, 0, 0);
            }
        }
    }
}

// Merged step: z<8 -> L0 at time t, z>=8 -> L1 at time t-1 (independent work).
__global__ __launch_bounds__(256, 2) void step_merged(
    int l0_active, int l1_active, int last0, int last1,
    const float* __restrict__ x, const ushort* __restrict__ Wx0F,
    const ushort* __restrict__ Wh0S, const float* __restrict__ b0,
    const ushort* __restrict__ h0_prev, float* __restrict__ c0,
    ushort* __restrict__ h0_out, float* __restrict__ oh0, float* __restrict__ oc0,
    const ushort* __restrict__ xin, const ushort* __restrict__ Wx1S,
    const ushort* __restrict__ Wh1S, const float* __restrict__ b1,
    const ushort* __restrict__ h1_prev, float* __restrict__ c1,
    ushort* __restrict__ h1_out, float* __restrict__ oh1, float* __restrict__ oc1)
{
    __shared__ __align__(16) ushort tile1[NCELL * TSTRIDE];
    __shared__ __align__(16) ushort tile2[NCELL * TSTRIDE];
    __shared__ __align__(16) ushort xa[4096];   // L0 im2col A-frags [r][lane][e]

    const int z = blockIdx.z;
    bool isL1; int b;
    if (l0_active && l1_active) { isL1 = (z >= 8); b = z & 7; }
    else                        { isL1 = (l1_active != 0); b = z; }

    const int tid = threadIdx.x;
    const int lane = tid & 63;
    const int fq = tid >> 6;            // wave id = f quad
    const int colA = lane & 15;
    const int quad = (lane >> 4) & 3;
    const int x0 = blockIdx.x * 16, y0 = blockIdx.y * 8;
    const int f = fq * 16 + colA;

    const ushort* h_prev = isL1 ? h1_prev : h0_prev;
    const float*  bias   = isL1 ? b1 : b0;
    float*        cbuf   = isL1 ? c1 : c0;
    ushort*       hout   = isL1 ? h1_out : h0_out;
    float* hf = isL1 ? (last1 ? oh1 : nullptr) : (last0 ? oh0 : nullptr);
    float* cf = isL1 ? (last1 ? oc1 : nullptr) : (last0 ? oc0 : nullptr);

    // ---- stage ----
    if (!isL1) {
        // build x im2col fragments: xa[r*512 + lane*8 + e]
        const float* xs = x + (size_t)b * 40960;
        for (int idx = tid; idx < 4096; idx += 256) {
            int e = idx & 7, li = (idx >> 3) & 63, r = idx >> 9;
            int ci = li & 15, qi = li >> 4;
            int k = qi * 8 + e;
            ushort val = 0;
            if (k < 9) {
                int dy = (k * 86) >> 8;          // k/3 for k<=8
                int dx = k - dy * 3;
                int y = y0 + r + dy - 1, xx = x0 + ci + dx - 1;
                if ((unsigned)y < 64u && (unsigned)xx < 64u)
                    val = f2bf(xs[(y << 6) + xx]);
            }
            xa[idx] = val;
        }
        if (h_prev) stage(h_prev + (size_t)b * 4096 * 64, tile1, y0, x0, tid);
    } else {
        stage(xin + (size_t)b * 4096 * 64, tile1, y0, x0, tid);
        if (h_prev) stage(h_prev + (size_t)b * 4096 * 64, tile2, y0, x0, tid);
    }
    __syncthreads();

    // ---- init accumulators with bias ----
    f32x4 acc[8][4];
    #pragma unroll
    for (int g = 0; g < 4; ++g) {
        float bv = bias[g * 64 + f];
        #pragma unroll
        for (int mt = 0; mt < 8; ++mt) {
            acc[mt][g][0] = bv; acc[mt][g][1] = bv;
            acc[mt][g][2] = bv; acc[mt][g][3] = bv;
        }
    }

    if (!isL1) {
        // x-conv via MFMA (K=32, taps 9..31 zero-padded in Wx0F)
        bf16x8 xb[4];
        #pragma unroll
        for (int g = 0; g < 4; ++g)
            xb[g] = *(const bf16x8*)&Wx0F[((fq * 4 + g) * 64 + lane) * 8];
        #pragma unroll
        for (int mt = 0; mt < 8; ++mt) {
            bf16x8 xaf = *(const bf16x8*)&xa[mt * 512 + lane * 8];
            #pragma unroll
            for (int g = 0; g < 4; ++g)
                acc[mt][g] = __builtin_amdgcn_mfma_f32_16x16x32_bf16(
                    xaf, xb[g], acc[mt][g], 0, 0, 0);
        }
        if (h_prev) conv8(tile1, Wh0S, acc, fq, lane);
    } else {
        conv8(tile1, Wx1S, acc, fq, lane);
        if (h_prev) conv8(tile2, Wh1S, acc, fq, lane);
    }

    // ---- LSTM pointwise epilogue ----
    #pragma unroll
    for (int mt = 0; mt < 8; ++mt) {
        const int y = y0 + mt;
        #pragma unroll
        for (int reg = 0; reg < 4; ++reg) {
            const int xx = x0 + quad * 4 + reg;
            const size_t pidx = ((size_t)b * 4096 + (y << 6) + xx) * 64 + f;
            float cp = h_prev ? cbuf[pidx] : 0.f;
            float iv = hsig(acc[mt][0][reg]);
            float fv = hsig(acc[mt][1][reg]);
            float gv = ftanh(acc[mt][2][reg]);
            float ov = hsig(acc[mt][3][reg]);
            float cn = fmaf(fv, cp, iv * gv);
            float hn = ov * ftanh(cn);
            cbuf[pidx] = cn;
            hout[pidx] = f2bf(hn);
            if (hf) { hf[pidx] = hn; cf[pidx] = cn; }
        }
    }
}

extern "C" void kernel_launch(void* const* d_in, const int* in_sizes, int n_in,
                              void* d_out, int out_size, void* d_ws, size_t ws_size,
                              hipStream_t stream) {
    const float* x   = (const float*)d_in[0];
    const float* Wx0 = (const float*)d_in[1];
    const float* Wh0 = (const float*)d_in[2];
    const float* b0  = (const float*)d_in[3];
    const float* Wx1 = (const float*)d_in[4];
    const float* Wh1 = (const float*)d_in[5];
    const float* b1  = (const float*)d_in[6];
    float* out = (float*)d_out;
    char* ws = (char*)d_ws;

    ushort* h0buf[2] = { (ushort*)ws, (ushort*)(ws + 4u * 1024 * 1024) };
    ushort* h1buf[2] = { (ushort*)(ws + 8u * 1024 * 1024), (ushort*)(ws + 12u * 1024 * 1024) };
    float* c0 = (float*)(ws + 16u * 1024 * 1024);
    float* c1 = (float*)(ws + 24u * 1024 * 1024);
    ushort* Wh0S = (ushort*)(ws + 32u * 1024 * 1024);
    ushort* Wx1S = Wh0S + 147456;
    ushort* Wh1S = Wx1S + 147456;
    ushort* Wx0F = Wh1S + 147456;   // 8192 ushorts

    prep_w<<<dim3(576, 4), 256, 0, stream>>>(Wh0, Wx1, Wh1, Wx0,
                                             Wh0S, Wx1S, Wh1S, Wx0F);

    for (int t = 0; t <= 10; ++t) {
        const int has0 = (t < 10), has1 = (t >= 1);
        const int s = t - 1;
        const int tx = has0 ? t : 9;
        dim3 grid(4, 8, (has0 && has1) ? 16 : 8);
        step_merged<<<grid, 256, 0, stream>>>(
            has0, has1, (t == 9), (s == 9),
            x + (size_t)tx * 4096, Wx0F,
            (t >= 1) ? Wh0S : nullptr, b0,
            (t >= 1 && has0) ? h0buf[(t - 1) & 1] : nullptr, c0,
            h0buf[t & 1], out, out + BHWF,
            has1 ? h0buf[s & 1] : nullptr, Wx1S,
            Wh1S, b1,
            (s >= 1) ? h1buf[(s - 1) & 1] : nullptr, c1,
            h1buf[s & 1], out + 2 * (size_t)BHWF, out + 3 * (size_t)BHWF);
    }
}

// Round 8
// 447.503 us; speedup vs baseline: 1.1029x; 1.0408x over previous
//
#include <hip/hip_runtime.h>

// ConvLSTM2D x2 encoder — bf16 MFMA implicit-GEMM, round 8.
// Round-7 model fix: MFMA floor is 12.2us/heavy-dispatch (not 3.5); the 4x gap
// is serialized B loads (regs exactly full -> no pipelining). Fix: B streamed
// via global_load_lds DMA (no VGPR cost) into 2x16KB LDS chunks; each wave
// stages its OWN fq slice (producer==consumer -> barrier-free), pipelined with
// explicit s_waitcnt vmcnt(4). c-state ws re-laid-out lane-linear (coalesced).

typedef __bf16 bf16x8 __attribute__((ext_vector_type(8)));
typedef float f32x4 __attribute__((ext_vector_type(4)));

#define BHWF (8 * 64 * 64 * 64)
#define TSTRIDE 72                // LDS cell stride (bf16 units)
#define NCELL 180                 // 10 rows x 18 cols halo tile

__device__ __forceinline__ float hsig(float x) {
    return fminf(fmaxf(fmaf(0.2f, x, 0.5f), 0.0f), 1.0f);
}

__device__ __forceinline__ float ftanh(float x) {
    float e = __expf(2.0f * x);
    return fmaf(-2.0f, __builtin_amdgcn_rcpf(e + 1.0f), 1.0f);
}

__device__ __forceinline__ ushort f2bf(float f) {
    unsigned u = __float_as_uint(f);
    return (ushort)((u + 0x7FFFu + ((u >> 16) & 1u)) >> 16);
}

// y=0..2: swizzle fp32 W[k=576][n=256] -> bf16 fragment-linear frames
//   (frame = tap*2+kc, 8192 ushorts each). y=3: Wx0 K=32-padded frames.
__global__ void prep_w(const float* __restrict__ s0, const float* __restrict__ s1,
                       const float* __restrict__ s2, const float* __restrict__ wx0,
                       ushort* __restrict__ d0, ushort* __restrict__ d1,
                       ushort* __restrict__ d2, ushort* __restrict__ dx0) {
    int o = blockIdx.x * 256 + threadIdx.x;
    if (blockIdx.y == 3) {
        if (o < 8192) {
            int e    = o & 7;
            int lane = (o >> 3) & 63;
            int g    = (o >> 9) & 3;
            int fq   = (o >> 11) & 3;
            int k = (lane >> 4) * 8 + e;
            int n = g * 64 + fq * 16 + (lane & 15);
            dx0[o] = (k < 9) ? f2bf(wx0[k * 256 + n]) : (ushort)0;
        }
        return;
    }
    const float* s[3] = { s0, s1, s2 };
    ushort* d[3] = { d0, d1, d2 };
    int e    = o & 7;
    int lane = (o >> 3) & 63;
    int g    = (o >> 9) & 3;
    int fq   = (o >> 11) & 3;
    int kc   = (o >> 13) & 1;
    int tap  = o >> 14;
    int n = g * 64 + fq * 16 + (lane & 15);
    int k = tap * 64 + kc * 32 + (lane >> 4) * 8 + e;
    d[blockIdx.y][o] = f2bf(s[blockIdx.y][k * 256 + n]);
}

// Stage 10x18 halo tile of bf16 [4096][64] image into LDS [cell][TSTRIDE].
__device__ __forceinline__ void stage(const ushort* __restrict__ src,
                                      ushort* __restrict__ tile,
                                      int y0, int x0, int tid) {
    for (int v = tid; v < NCELL * 8; v += 256) {
        int cell = v >> 3, j = v & 7;
        int r = cell / 18, cc = cell - r * 18;
        int y = y0 - 1 + r, xx = x0 - 1 + cc;
        uint4 dv = make_uint4(0u, 0u, 0u, 0u);
        if ((unsigned)y < 64u && (unsigned)xx < 64u)
            dv = ((const uint4*)src)[(size_t)((y << 6) + xx) * 8 + j];
        *(uint4*)&tile[cell * TSTRIDE + j * 8] = dv;
    }
}

// Async-stage this wave's 4KB fq-slice (4 x 1KB bursts): lane L moves 16B.
__device__ __forceinline__ void dma4(const ushort* __restrict__ src, ushort* dst) {
#pragma unroll
    for (int g = 0; g < 4; ++g)
        __builtin_amdgcn_global_load_lds(
            (const __attribute__((address_space(1))) unsigned int*)(src + g * 512),
            (__attribute__((address_space(3))) unsigned int*)(dst + g * 512),
            16, 0, 0);
}

// 3x3x64 conv, M=128/wave, B streamed via wave-private DMA double-buffer.
// Chunk c in 0..17: kc=c/9, dx=(c%9)/3, dy=c%3, frame=(dy*3+dx)*2+kc.
__device__ __forceinline__ void conv_stream(const ushort* __restrict__ tile,
                                            const ushort* __restrict__ WS,
                                            ushort* __restrict__ bbuf,
                                            f32x4 (&acc)[8][4],
                                            int fq, int lane) {
    const int colA = lane & 15;
    const int quad = (lane >> 4) & 3;
    const int sl = fq * 2048 + lane * 8;    // wave slice offset within a chunk
    dma4(WS + sl, bbuf + sl);               // chunk 0 = frame 0
    bf16x8 A[10];
#pragma unroll
    for (int c = 0; c < 18; ++c) {
        if (c < 17) {
            const int c1 = c + 1;
            const int kc1 = c1 / 9, dx1 = (c1 % 9) / 3, dy1 = c1 % 3;
            dma4(WS + (size_t)((dy1 * 3 + dx1) * 2 + kc1) * 8192 + sl,
                 bbuf + (c1 & 1) * 8192 + sl);
            __asm__ volatile("s_waitcnt vmcnt(4)" ::: "memory");
        } else {
            __asm__ volatile("s_waitcnt vmcnt(0)" ::: "memory");
        }
        const int kc = c / 9, dx = (c % 9) / 3, dy = c % 3;
        if (dy == 0) {
#pragma unroll
            for (int r = 0; r < 10; ++r)
                A[r] = *(const bf16x8*)&tile[(r * 18 + colA + dx) * TSTRIDE + kc * 32 + quad * 8];
        }
        const ushort* bp = bbuf + (c & 1) * 8192 + sl;
        bf16x8 B0 = *(const bf16x8*)&bp[0];
        bf16x8 B1 = *(const bf16x8*)&bp[512];
        bf16x8 B2 = *(const bf16x8*)&bp[1024];
        bf16x8 B3 = *(const bf16x8*)&bp[1536];
#pragma unroll
        for (int mt = 0; mt < 8; ++mt) {
            acc[mt][0] = __builtin_amdgcn_mfma_f32_16x16x32_bf16(A[mt + dy], B0, acc[mt][0], 0, 0, 0);
            acc[mt][1] = __builtin_amdgcn_mfma_f32_16x16x32_bf16(A[mt + dy], B1, acc[mt][1], 0, 0, 0);
            acc[mt][2] = __builtin_amdgcn_mfma_f32_16x16x32_bf16(A[mt + dy], B2, acc[mt][2], 0, 0, 0);
            acc[mt][3] = __builtin_amdgcn_mfma_f32_16x16x32_bf16(A[mt + dy], B3, acc[mt][3], 0, 0, 0);
        }
    }
}

// Merged step: z<8 -> L0 at time t, z>=8 -> L1 at time t-1 (independent work).
__global__ __launch_bounds__(256, 2) void step_merged(
    int l0_active, int l1_active, int last0, int last1,
    const float* __restrict__ x, const ushort* __restrict__ Wx0F,
    const ushort* __restrict__ Wh0S, const float* __restrict__ b0,
    const ushort* __restrict__ h0_prev, float* __restrict__ c0,
    ushort* __restrict__ h0_out, float* __restrict__ oh0, float* __restrict__ oc0,
    const ushort* __restrict__ xin, const ushort* __restrict__ Wx1S,
    const ushort* __restrict__ Wh1S, const float* __restrict__ b1,
    const ushort* __restrict__ h1_prev, float* __restrict__ c1,
    ushort* __restrict__ h1_out, float* __restrict__ oh1, float* __restrict__ oc1)
{
    __shared__ __align__(16) ushort tile[NCELL * TSTRIDE];   // 25,920 B
    __shared__ __align__(16) ushort bbuf[2 * 8192];          // 32,768 B B-dbuf
    __shared__ __align__(16) ushort xa[4096];                // 8,192 B  L0 im2col

    const int z = blockIdx.z;
    bool isL1; int b;
    if (l0_active && l1_active) { isL1 = (z >= 8); b = z & 7; }
    else                        { isL1 = (l1_active != 0); b = z; }

    const int tid = threadIdx.x;
    const int lane = tid & 63;
    const int fq = tid >> 6;            // wave id = f quad
    const int colA = lane & 15;
    const int quad = (lane >> 4) & 3;
    const int x0 = blockIdx.x * 16, y0 = blockIdx.y * 8;
    const int f = fq * 16 + colA;

    const ushort* h_prev = isL1 ? h1_prev : h0_prev;
    const float*  bias   = isL1 ? b1 : b0;
    float*        cbuf   = isL1 ? c1 : c0;
    ushort*       hout   = isL1 ? h1_out : h0_out;
    float* hf = isL1 ? (last1 ? oh1 : nullptr) : (last0 ? oh0 : nullptr);
    float* cf = isL1 ? (last1 ? oc1 : nullptr) : (last0 ? oc0 : nullptr);

    // ---- stage first A source ----
    if (!isL1) {
        const float* xs = x + (size_t)b * 40960;
        for (int idx = tid; idx < 4096; idx += 256) {
            int e = idx & 7, li = (idx >> 3) & 63, r = idx >> 9;
            int ci = li & 15, qi = li >> 4;
            int k = qi * 8 + e;
            ushort val = 0;
            if (k < 9) {
                int dy = (k * 86) >> 8;
                int dx = k - dy * 3;
                int y = y0 + r + dy - 1, xx = x0 + ci + dx - 1;
                if ((unsigned)y < 64u && (unsigned)xx < 64u)
                    val = f2bf(xs[(y << 6) + xx]);
            }
            xa[idx] = val;
        }
        if (h_prev) stage(h_prev + (size_t)b * 4096 * 64, tile, y0, x0, tid);
    } else {
        stage(xin + (size_t)b * 4096 * 64, tile, y0, x0, tid);
    }
    __syncthreads();

    // ---- init accumulators with bias ----
    f32x4 acc[8][4];
#pragma unroll
    for (int g = 0; g < 4; ++g) {
        float bv = bias[g * 64 + f];
#pragma unroll
        for (int mt = 0; mt < 8; ++mt) {
            acc[mt][g][0] = bv; acc[mt][g][1] = bv;
            acc[mt][g][2] = bv; acc[mt][g][3] = bv;
        }
    }

    if (!isL1) {
        // x-conv via MFMA (K=32-padded Wx0 frames)
        bf16x8 xb[4];
#pragma unroll
        for (int g = 0; g < 4; ++g)
            xb[g] = *(const bf16x8*)&Wx0F[((fq * 4 + g) * 64 + lane) * 8];
#pragma unroll
        for (int mt = 0; mt < 8; ++mt) {
            bf16x8 xaf = *(const bf16x8*)&xa[mt * 512 + lane * 8];
#pragma unroll
            for (int g = 0; g < 4; ++g)
                acc[mt][g] = __builtin_amdgcn_mfma_f32_16x16x32_bf16(
                    xaf, xb[g], acc[mt][g], 0, 0, 0);
        }
        if (h_prev) conv_stream(tile, Wh0S, bbuf, acc, fq, lane);
    } else {
        conv_stream(tile, Wx1S, bbuf, acc, fq, lane);
        if (h_prev) {
            __syncthreads();
            stage(h_prev + (size_t)b * 4096 * 64, tile, y0, x0, tid);
            __syncthreads();
            conv_stream(tile, Wh1S, bbuf, acc, fq, lane);
        }
    }

    // ---- LSTM pointwise epilogue ----
    // cbuf private layout (lane-linear): ((((b*4+fq)*64+y)*4+reg)*16 + x0/4+quad)*16 + colA
#pragma unroll
    for (int mt = 0; mt < 8; ++mt) {
        const int y = y0 + mt;
#pragma unroll
        for (int reg = 0; reg < 4; ++reg) {
            const int xx = x0 + quad * 4 + reg;
            const size_t cidx = ((size_t)((((b * 4 + fq) * 64 + y) * 4 + reg) * 16
                                 + (x0 >> 2) + quad)) * 16 + colA;
            const size_t pidx = ((size_t)b * 4096 + (y << 6) + xx) * 64 + f;
            float cp = h_prev ? cbuf[cidx] : 0.f;
            float iv = hsig(acc[mt][0][reg]);
            float fv = hsig(acc[mt][1][reg]);
            float gv = ftanh(acc[mt][2][reg]);
            float ov = hsig(acc[mt][3][reg]);
            float cn = fmaf(fv, cp, iv * gv);
            float hn = ov * ftanh(cn);
            cbuf[cidx] = cn;
            hout[pidx] = f2bf(hn);
            if (hf) { hf[pidx] = hn; cf[pidx] = cn; }
        }
    }
}

extern "C" void kernel_launch(void* const* d_in, const int* in_sizes, int n_in,
                              void* d_out, int out_size, void* d_ws, size_t ws_size,
                              hipStream_t stream) {
    const float* x   = (const float*)d_in[0];
    const float* Wx0 = (const float*)d_in[1];
    const float* Wh0 = (const float*)d_in[2];
    const float* b0  = (const float*)d_in[3];
    const float* Wx1 = (const float*)d_in[4];
    const float* Wh1 = (const float*)d_in[5];
    const float* b1  = (const float*)d_in[6];
    float* out = (float*)d_out;
    char* ws = (char*)d_ws;

    ushort* h0buf[2] = { (ushort*)ws, (ushort*)(ws + 4u * 1024 * 1024) };
    ushort* h1buf[2] = { (ushort*)(ws + 8u * 1024 * 1024), (ushort*)(ws + 12u * 1024 * 1024) };
    float* c0 = (float*)(ws + 16u * 1024 * 1024);
    float* c1 = (float*)(ws + 24u * 1024 * 1024);
    ushort* Wh0S = (ushort*)(ws + 32u * 1024 * 1024);
    ushort* Wx1S = Wh0S + 147456;
    ushort* Wh1S = Wx1S + 147456;
    ushort* Wx0F = Wh1S + 147456;

    prep_w<<<dim3(576, 4), 256, 0, stream>>>(Wh0, Wx1, Wh1, Wx0,
                                             Wh0S, Wx1S, Wh1S, Wx0F);

    for (int t = 0; t <= 10; ++t) {
        const int has0 = (t < 10), has1 = (t >= 1);
        const int s = t - 1;
        const int tx = has0 ? t : 9;
        dim3 grid(4, 8, (has0 && has1) ? 16 : 8);
        step_merged<<<grid, 256, 0, stream>>>(
            has0, has1, (t == 9), (s == 9),
            x + (size_t)tx * 4096, Wx0F,
            (t >= 1) ? Wh0S : nullptr, b0,
            (t >= 1 && has0) ? h0buf[(t - 1) & 1] : nullptr, c0,
            h0buf[t & 1], out, out + BHWF,
            has1 ? h0buf[s & 1] : nullptr, Wx1S,
            Wh1S, b1,
            (s >= 1) ? h1buf[(s - 1) & 1] : nullptr, c1,
            h1buf[s & 1], out + 2 * (size_t)BHWF, out + 3 * (size_t)BHWF);
    }
}